// Round 2
// baseline (1978.608 us; speedup 1.0000x reference)
//
#include <hip/hip_runtime.h>

#define N_NODES   100000
#define N_EDGES   3200000
#define D_IN      128
#define H1F       32
#define H2F       64
#define N_CLASSES 10
#define N_GRAPHS  64

// ---------------- degree / normalization ----------------
__global__ void k_deg_init(float* deg) {
    int i = blockIdx.x * blockDim.x + threadIdx.x;
    if (i < N_NODES) deg[i] = 1.0f;   // self-loop contributes 1
}

__global__ void k_deg_accum(const int* __restrict__ row, float* deg) {
    int e = blockIdx.x * blockDim.x + threadIdx.x;
    if (e < N_EDGES) atomicAdd(&deg[row[e]], 1.0f);
}

__global__ void k_dis(float* deg_dis) {
    int i = blockIdx.x * blockDim.x + threadIdx.x;
    if (i < N_NODES) deg_dis[i] = rsqrtf(deg_dis[i]);
}

// ---------------- linear layers ----------------
// h1[n][f] = sum_k x[n][k] * W1[f][k] + b1[f]
__global__ __launch_bounds__(256) void k_lin1(const float* __restrict__ x,
        const float* __restrict__ W1, const float* __restrict__ b1,
        float* __restrict__ h1) {
    __shared__ float w1t[D_IN][H1F + 1];   // transposed, padded
    __shared__ float xs[8][D_IN];
    int tid = threadIdx.x;
    for (int idx = tid; idx < H1F * D_IN; idx += 256) {
        int f = idx >> 7, k = idx & 127;
        w1t[k][f] = W1[idx];
    }
    long long nbase = (long long)blockIdx.x * 8;
    for (int idx = tid; idx < 8 * D_IN; idx += 256) {
        int nn = idx >> 7, k = idx & 127;
        long long n = nbase + nn;
        xs[nn][k] = (n < N_NODES) ? x[n * D_IN + k] : 0.0f;
    }
    __syncthreads();
    int f = tid & 31, sub = tid >> 5;
    long long n = nbase + sub;
    if (n < N_NODES) {
        float acc = 0.f;
        #pragma unroll
        for (int k = 0; k < D_IN; ++k) acc += xs[sub][k] * w1t[k][f];
        h1[n * H1F + f] = acc + b1[f];
    }
}

// h2[n][f] = sum_k relu(a1[n][k]) * W2[f][k] + b2[f]
__global__ __launch_bounds__(256) void k_lin2(const float* __restrict__ a1,
        const float* __restrict__ W2, const float* __restrict__ b2,
        float* __restrict__ h2) {
    __shared__ float w2t[H1F][H2F + 1];
    __shared__ float as[4][H1F];
    int tid = threadIdx.x;
    for (int idx = tid; idx < H2F * H1F; idx += 256) {
        int fo = idx >> 5, k = idx & 31;
        w2t[k][fo] = W2[idx];
    }
    long long nbase = (long long)blockIdx.x * 4;
    for (int idx = tid; idx < 4 * H1F; idx += 256) {
        int nn = idx >> 5, k = idx & 31;
        long long n = nbase + nn;
        as[nn][k] = (n < N_NODES) ? fmaxf(a1[n * H1F + k], 0.f) : 0.f;
    }
    __syncthreads();
    int f = tid & 63, sub = tid >> 6;
    long long n = nbase + sub;
    if (n < N_NODES) {
        float acc = 0.f;
        #pragma unroll
        for (int k = 0; k < H1F; ++k) acc += as[sub][k] * w2t[k][f];
        h2[n * H2F + f] = acc + b2[f];
    }
}

// ---------------- message passing ----------------
// self-loop term: a[n][f] = h[n][f] * dis[n]^2   (norm = dis[n]*dis[n])
template<int F>
__global__ void k_init_a(const float* __restrict__ h, const float* __restrict__ dis,
                         float* __restrict__ a) {
    long long idx = (long long)blockIdx.x * blockDim.x + threadIdx.x;
    if (idx < (long long)N_NODES * F) {
        int n = (int)(idx / F);
        float d = dis[n];
        a[idx] = h[idx] * d * d;
    }
}

// a[col][f] += dis[row]*dis[col] * h[row][f]
template<int F>
__global__ __launch_bounds__(256) void k_scatter(const int* __restrict__ row,
        const int* __restrict__ col, const float* __restrict__ dis,
        const float* __restrict__ h, float* __restrict__ a) {
    long long idx = (long long)blockIdx.x * blockDim.x + threadIdx.x;
    if (idx >= (long long)N_EDGES * F) return;
    int e = (int)(idx / F);
    int f = (int)(idx & (F - 1));
    int r = row[e], c = col[e];
    float nrm = dis[r] * dis[c];
    atomicAdd(&a[(long long)c * F + f], nrm * h[(long long)r * F + f]);
}

// ---------------- pooling ----------------
__global__ void k_pool_zero(float* sums, float* counts) {
    int i = blockIdx.x * blockDim.x + threadIdx.x;
    if (i < N_GRAPHS * H2F) sums[i] = 0.f;
    if (i < N_GRAPHS) counts[i] = 0.f;
}

__global__ void k_counts(const int* __restrict__ batch, float* counts) {
    int i = blockIdx.x * blockDim.x + threadIdx.x;
    if (i < N_NODES) atomicAdd(&counts[batch[i]], 1.0f);
}

#define POOL_CHUNK 256
// batch is sorted: accumulate per-thread runs, flush one atomic per graph change
__global__ __launch_bounds__(256) void k_pool(const float* __restrict__ a2,
        const int* __restrict__ batch, float* __restrict__ sums) {
    int f = threadIdx.x & 63, sub = threadIdx.x >> 6;
    long long n0 = (long long)blockIdx.x * POOL_CHUNK;
    float acc = 0.f; int gcur = -1;
    for (int i = sub; i < POOL_CHUNK; i += 4) {
        long long n = n0 + i;
        if (n >= N_NODES) break;
        int g = batch[n];
        if (g != gcur) {
            if (gcur >= 0) atomicAdd(&sums[gcur * H2F + f], acc);
            acc = 0.f; gcur = g;
        }
        acc += fmaxf(a2[n * H2F + f], 0.f);   // relu(conv2 out)
    }
    if (gcur >= 0) atomicAdd(&sums[gcur * H2F + f], acc);
}

// ---------------- final: mean, linear, softmax ----------------
__global__ __launch_bounds__(1024) void k_final(const float* __restrict__ sums,
        const float* __restrict__ counts, const float* __restrict__ Wf,
        const float* __restrict__ bf, float* __restrict__ out) {
    __shared__ float l[N_GRAPHS * N_CLASSES];
    int tid = threadIdx.x;
    if (tid < N_GRAPHS * N_CLASSES) {
        int g = tid / N_CLASSES, c = tid % N_CLASSES;
        float cnt = fmaxf(counts[g], 1.0f);
        float acc = bf[c];
        for (int f = 0; f < H2F; ++f)
            acc += (sums[g * H2F + f] / cnt) * Wf[c * H2F + f];
        l[tid] = acc;
    }
    __syncthreads();
    if (tid < N_GRAPHS) {
        float m = -1e30f;
        for (int c = 0; c < N_CLASSES; ++c) m = fmaxf(m, l[tid * N_CLASSES + c]);
        float s = 0.f;
        float ex[N_CLASSES];
        for (int c = 0; c < N_CLASSES; ++c) { ex[c] = expf(l[tid * N_CLASSES + c] - m); s += ex[c]; }
        for (int c = 0; c < N_CLASSES; ++c) out[tid * N_CLASSES + c] = ex[c] / s;
    }
}

extern "C" void kernel_launch(void* const* d_in, const int* in_sizes, int n_in,
                              void* d_out, int out_size, void* d_ws, size_t ws_size,
                              hipStream_t stream) {
    const float* x     = (const float*)d_in[0];
    const int*   ei    = (const int*)d_in[1];    // int64 in ref -> int32 in harness
    const int*   batch = (const int*)d_in[2];
    const float* W1    = (const float*)d_in[3];
    const float* b1    = (const float*)d_in[4];
    const float* W2    = (const float*)d_in[5];
    const float* b2    = (const float*)d_in[6];
    const float* Wf    = (const float*)d_in[7];
    const float* bf    = (const float*)d_in[8];
    float* out = (float*)d_out;
    float* ws  = (float*)d_ws;

    const int* row = ei;            // edge_index[0,:]
    const int* col = ei + N_EDGES;  // edge_index[1,:]

    // workspace layout (floats); a2 aliases [h1|a1] which are dead by then
    float* dis    = ws;                   // 100352
    float* h1     = ws + 100352;          // 3.2M
    float* a1     = h1 + N_NODES * H1F;   // 3.2M
    float* a2     = h1;                   // 6.4M alias
    float* h2     = a1 + N_NODES * H1F;   // 6.4M
    float* sums   = h2 + N_NODES * H2F;   // 4096
    float* counts = sums + N_GRAPHS * H2F;// 64
    // total ~51.6 MB

    // deg -> dis
    k_deg_init<<<(N_NODES + 255) / 256, 256, 0, stream>>>(dis);
    k_deg_accum<<<(N_EDGES + 255) / 256, 256, 0, stream>>>(row, dis);
    k_dis<<<(N_NODES + 255) / 256, 256, 0, stream>>>(dis);

    // layer 1
    k_lin1<<<(N_NODES + 7) / 8, 256, 0, stream>>>(x, W1, b1, h1);
    k_init_a<H1F><<<(int)(((long long)N_NODES * H1F + 255) / 256), 256, 0, stream>>>(h1, dis, a1);
    k_scatter<H1F><<<(int)(((long long)N_EDGES * H1F + 255) / 256), 256, 0, stream>>>(row, col, dis, h1, a1);

    // layer 2 (relu fused into lin2 load)
    k_lin2<<<(N_NODES + 3) / 4, 256, 0, stream>>>(a1, W2, b2, h2);
    k_init_a<H2F><<<(int)(((long long)N_NODES * H2F + 255) / 256), 256, 0, stream>>>(h2, dis, a2);
    k_scatter<H2F><<<(int)(((long long)N_EDGES * H2F + 255) / 256), 256, 0, stream>>>(row, col, dis, h2, a2);

    // pooling (relu fused), then final linear+softmax
    k_pool_zero<<<(N_GRAPHS * H2F + 255) / 256, 256, 0, stream>>>(sums, counts);
    k_counts<<<(N_NODES + 255) / 256, 256, 0, stream>>>(batch, counts);
    k_pool<<<(N_NODES + POOL_CHUNK - 1) / POOL_CHUNK, 256, 0, stream>>>(a2, batch, sums);
    k_final<<<1, 640, 0, stream>>>(sums, counts, Wf, bf, out);
}

// Round 3
// 1366.781 us; speedup vs baseline: 1.4476x; 1.4476x over previous
//
#include <hip/hip_runtime.h>

#define N_NODES   100000
#define N_EDGES   3200000
#define D_IN      128
#define H1F       32
#define H2F       64
#define N_CLASSES 10
#define N_GRAPHS  64

// ---------------- init: zero counters ----------------
__global__ void k_zero(int* degc, int* cnt, int* fpos, float* sums, float* counts) {
    int i = blockIdx.x * blockDim.x + threadIdx.x;
    if (i < N_NODES) { degc[i] = 0; cnt[i] = 0; fpos[i] = 0; }
    if (i < N_GRAPHS * H2F) sums[i] = 0.f;
    if (i < N_GRAPHS) counts[i] = 0.f;
}

// deg by row (source), in-degree histogram by col (dest)
__global__ void k_count(const int* __restrict__ row, const int* __restrict__ col,
                        int* degc, int* cnt) {
    int e = blockIdx.x * blockDim.x + threadIdx.x;
    if (e < N_EDGES) {
        atomicAdd(&degc[row[e]], 1);
        atomicAdd(&cnt[col[e]], 1);
    }
}

__global__ void k_dis(const int* __restrict__ degc, float* dis) {
    int i = blockIdx.x * blockDim.x + threadIdx.x;
    if (i < N_NODES) dis[i] = rsqrtf((float)(1 + degc[i]));  // +1 self-loop
}

// ---------------- exclusive scan of cnt -> off ----------------
// 256 threads x 4 elems = 1024 per block
__global__ __launch_bounds__(256) void k_scan1(const int* __restrict__ cnt,
        int* __restrict__ off, int* __restrict__ bsum) {
    __shared__ int tsum[256];
    int t = threadIdx.x;
    int base = blockIdx.x * 1024 + t * 4;
    int v[4]; int s = 0;
    #pragma unroll
    for (int i = 0; i < 4; ++i) { int idx = base + i; v[i] = (idx < N_NODES) ? cnt[idx] : 0; s += v[i]; }
    tsum[t] = s; __syncthreads();
    for (int ofs = 1; ofs < 256; ofs <<= 1) {
        int val = (t >= ofs) ? tsum[t - ofs] : 0;
        __syncthreads();
        tsum[t] += val;
        __syncthreads();
    }
    int ex = tsum[t] - s;
    if (t == 255) bsum[blockIdx.x] = tsum[255];
    #pragma unroll
    for (int i = 0; i < 4; ++i) { int idx = base + i; if (idx < N_NODES) { off[idx] = ex; ex += v[i]; } }
}

__global__ void k_scan2(int* bsum, int nb) {
    __shared__ int sh[128];
    int t = threadIdx.x;
    int v = (t < nb) ? bsum[t] : 0;
    sh[t] = v; __syncthreads();
    for (int ofs = 1; ofs < 128; ofs <<= 1) {
        int val = (t >= ofs) ? sh[t - ofs] : 0;
        __syncthreads();
        sh[t] += val;
        __syncthreads();
    }
    if (t < nb) bsum[t] = sh[t] - v;  // exclusive
}

__global__ __launch_bounds__(256) void k_scan3(int* off, const int* __restrict__ bsum) {
    int base = blockIdx.x * 1024 + threadIdx.x * 4;
    int b = bsum[blockIdx.x];
    #pragma unroll
    for (int i = 0; i < 4; ++i) { int idx = base + i; if (idx < N_NODES) off[idx] += b; }
    if (blockIdx.x == 0 && threadIdx.x == 0) off[N_NODES] = N_EDGES;
}

// ---------------- CSR fill (sorted by col) ----------------
__global__ void k_fill(const int* __restrict__ row, const int* __restrict__ col,
                       const int* __restrict__ off, int* fpos, int* __restrict__ srcw) {
    int e = blockIdx.x * blockDim.x + threadIdx.x;
    if (e >= N_EDGES) return;
    int c = col[e];
    int p = off[c] + atomicAdd(&fpos[c], 1);
    srcw[p] = row[e];
}

// ---------------- linear layers (epilogue: scale by dis[n]) ----------------
// hs1[n][f] = dis[n] * (sum_k x[n][k]*W1[f][k] + b1[f])
__global__ __launch_bounds__(256) void k_lin1(const float* __restrict__ x,
        const float* __restrict__ W1, const float* __restrict__ b1,
        const float* __restrict__ dis, float* __restrict__ hs1) {
    __shared__ float w1t[D_IN][H1F + 1];
    __shared__ float xs[8][D_IN];
    int tid = threadIdx.x;
    for (int idx = tid; idx < H1F * D_IN; idx += 256) {
        int f = idx >> 7, k = idx & 127;
        w1t[k][f] = W1[idx];
    }
    long long nbase = (long long)blockIdx.x * 8;
    for (int idx = tid; idx < 8 * D_IN; idx += 256) {
        int nn = idx >> 7, k = idx & 127;
        long long n = nbase + nn;
        xs[nn][k] = (n < N_NODES) ? x[n * D_IN + k] : 0.0f;
    }
    __syncthreads();
    int f = tid & 31, sub = tid >> 5;
    long long n = nbase + sub;
    if (n < N_NODES) {
        float acc = 0.f;
        #pragma unroll
        for (int k = 0; k < D_IN; ++k) acc += xs[sub][k] * w1t[k][f];
        hs1[n * H1F + f] = dis[n] * (acc + b1[f]);
    }
}

// hs2[n][f] = dis[n] * (sum_k relu(a1[n][k])*W2[f][k] + b2[f])
__global__ __launch_bounds__(256) void k_lin2(const float* __restrict__ a1,
        const float* __restrict__ W2, const float* __restrict__ b2,
        const float* __restrict__ dis, float* __restrict__ hs2) {
    __shared__ float w2t[H1F][H2F + 1];
    __shared__ float as[4][H1F];
    int tid = threadIdx.x;
    for (int idx = tid; idx < H2F * H1F; idx += 256) {
        int fo = idx >> 5, k = idx & 31;
        w2t[k][fo] = W2[idx];
    }
    long long nbase = (long long)blockIdx.x * 4;
    for (int idx = tid; idx < 4 * H1F; idx += 256) {
        int nn = idx >> 5, k = idx & 31;
        long long n = nbase + nn;
        as[nn][k] = (n < N_NODES) ? fmaxf(a1[n * H1F + k], 0.f) : 0.f;
    }
    __syncthreads();
    int f = tid & 63, sub = tid >> 6;
    long long n = nbase + sub;
    if (n < N_NODES) {
        float acc = 0.f;
        #pragma unroll
        for (int k = 0; k < H1F; ++k) acc += as[sub][k] * w2t[k][f];
        hs2[n * H2F + f] = dis[n] * (acc + b2[f]);
    }
}

// ---------------- gather (SpMM, CSR by destination) ----------------
// a[c][f] = dis[c] * ( hs[c][f] + sum_{j in in(c)} hs[src_j][f] )
// F=32: one wave per node, 2 edges per iteration (lanes 0-31 / 32-63)
__global__ __launch_bounds__(256) void k_gather32(const int* __restrict__ srcw,
        const int* __restrict__ off, const float* __restrict__ dis,
        const float* __restrict__ hs, float* __restrict__ a) {
    int lane = threadIdx.x & 63;
    int c = (blockIdx.x * 256 + threadIdx.x) >> 6;
    if (c >= N_NODES) return;
    int f = lane & 31, half = lane >> 5;
    int s = off[c], e = off[c + 1];
    float acc = half ? 0.f : hs[c * H1F + f];
    for (int j = s + half; j < e; j += 2)
        acc += hs[srcw[j] * H1F + f];
    acc += __shfl_xor(acc, 32);
    if (half == 0) a[c * H1F + f] = dis[c] * acc;
}

// F=64: one wave per node, one edge per iteration (256B coalesced), 2-way unrolled
__global__ __launch_bounds__(256) void k_gather64(const int* __restrict__ srcw,
        const int* __restrict__ off, const float* __restrict__ dis,
        const float* __restrict__ hs, float* __restrict__ a) {
    int lane = threadIdx.x & 63;
    int c = (blockIdx.x * 256 + threadIdx.x) >> 6;
    if (c >= N_NODES) return;
    int s = off[c], e = off[c + 1];
    float acc = hs[c * H2F + lane];
    int j = s;
    for (; j + 1 < e; j += 2) {
        int s0 = srcw[j], s1 = srcw[j + 1];
        acc += hs[s0 * H2F + lane];
        acc += hs[s1 * H2F + lane];
    }
    if (j < e) acc += hs[srcw[j] * H2F + lane];
    a[c * H2F + lane] = dis[c] * acc;
}

// ---------------- pooling ----------------
__global__ void k_counts(const int* __restrict__ batch, float* counts) {
    int i = blockIdx.x * blockDim.x + threadIdx.x;
    if (i < N_NODES) atomicAdd(&counts[batch[i]], 1.0f);
}

#define POOL_CHUNK 256
__global__ __launch_bounds__(256) void k_pool(const float* __restrict__ a2,
        const int* __restrict__ batch, float* __restrict__ sums) {
    int f = threadIdx.x & 63, sub = threadIdx.x >> 6;
    long long n0 = (long long)blockIdx.x * POOL_CHUNK;
    float acc = 0.f; int gcur = -1;
    for (int i = sub; i < POOL_CHUNK; i += 4) {
        long long n = n0 + i;
        if (n >= N_NODES) break;
        int g = batch[n];
        if (g != gcur) {
            if (gcur >= 0) atomicAdd(&sums[gcur * H2F + f], acc);
            acc = 0.f; gcur = g;
        }
        acc += fmaxf(a2[n * H2F + f], 0.f);   // relu(conv2 out)
    }
    if (gcur >= 0) atomicAdd(&sums[gcur * H2F + f], acc);
}

// ---------------- final: mean, linear, softmax ----------------
__global__ __launch_bounds__(1024) void k_final(const float* __restrict__ sums,
        const float* __restrict__ counts, const float* __restrict__ Wf,
        const float* __restrict__ bf, float* __restrict__ out) {
    __shared__ float l[N_GRAPHS * N_CLASSES];
    int tid = threadIdx.x;
    if (tid < N_GRAPHS * N_CLASSES) {
        int g = tid / N_CLASSES, c = tid % N_CLASSES;
        float cnt = fmaxf(counts[g], 1.0f);
        float acc = bf[c];
        for (int f = 0; f < H2F; ++f)
            acc += (sums[g * H2F + f] / cnt) * Wf[c * H2F + f];
        l[tid] = acc;
    }
    __syncthreads();
    if (tid < N_GRAPHS) {
        float m = -1e30f;
        for (int c = 0; c < N_CLASSES; ++c) m = fmaxf(m, l[tid * N_CLASSES + c]);
        float s = 0.f;
        float ex[N_CLASSES];
        for (int c = 0; c < N_CLASSES; ++c) { ex[c] = expf(l[tid * N_CLASSES + c] - m); s += ex[c]; }
        for (int c = 0; c < N_CLASSES; ++c) out[tid * N_CLASSES + c] = ex[c] / s;
    }
}

extern "C" void kernel_launch(void* const* d_in, const int* in_sizes, int n_in,
                              void* d_out, int out_size, void* d_ws, size_t ws_size,
                              hipStream_t stream) {
    const float* x     = (const float*)d_in[0];
    const int*   ei    = (const int*)d_in[1];
    const int*   batch = (const int*)d_in[2];
    const float* W1    = (const float*)d_in[3];
    const float* b1    = (const float*)d_in[4];
    const float* W2    = (const float*)d_in[5];
    const float* b2    = (const float*)d_in[6];
    const float* Wf    = (const float*)d_in[7];
    const float* bf    = (const float*)d_in[8];
    float* out = (float*)d_out;

    const int* row = ei;            // edge_index[0,:] (source)
    const int* col = ei + N_EDGES;  // edge_index[1,:] (dest)

    // workspace layout
    int*   wsi   = (int*)d_ws;
    int*   degc  = wsi;                    // 100000
    int*   cnt   = degc + N_NODES;         // 100000
    int*   fpos  = cnt  + N_NODES;         // 100000
    int*   off   = fpos + N_NODES;         // 100001 (+1 pad)
    int*   bsum  = off  + N_NODES + 2;     // 128
    int*   srcw  = bsum + 128;             // 3200000
    float* dis   = (float*)(srcw + N_EDGES);        // 100000
    float* hs1   = dis + N_NODES;                   // 3.2M
    float* a1    = hs1 + (long long)N_NODES * H1F;  // 3.2M
    float* hs2   = a1  + (long long)N_NODES * H1F;  // 6.4M
    float* a2    = hs1;                             // alias over hs1+a1 (both dead)
    float* sums  = hs2 + (long long)N_NODES * H2F;  // 4096
    float* cnts  = sums + N_GRAPHS * H2F;           // 64
    // total ~66 MB

    const int nb = (N_NODES + 1023) / 1024;  // 98 scan blocks

    // CSR build + normalization
    k_zero<<<(N_NODES + 255) / 256, 256, 0, stream>>>(degc, cnt, fpos, sums, cnts);
    k_count<<<(N_EDGES + 255) / 256, 256, 0, stream>>>(row, col, degc, cnt);
    k_dis<<<(N_NODES + 255) / 256, 256, 0, stream>>>(degc, dis);
    k_scan1<<<nb, 256, 0, stream>>>(cnt, off, bsum);
    k_scan2<<<1, 128, 0, stream>>>(bsum, nb);
    k_scan3<<<nb, 256, 0, stream>>>(off, bsum);
    k_fill<<<(N_EDGES + 255) / 256, 256, 0, stream>>>(row, col, off, fpos, srcw);

    // layer 1
    k_lin1<<<(N_NODES + 7) / 8, 256, 0, stream>>>(x, W1, b1, dis, hs1);
    k_gather32<<<(N_NODES * 64 + 255) / 256, 256, 0, stream>>>(srcw, off, dis, hs1, a1);

    // layer 2
    k_lin2<<<(N_NODES + 3) / 4, 256, 0, stream>>>(a1, W2, b2, dis, hs2);
    k_gather64<<<(N_NODES * 64 + 255) / 256, 256, 0, stream>>>(srcw, off, dis, hs2, a2);

    // pooling + head
    k_counts<<<(N_NODES + 255) / 256, 256, 0, stream>>>(batch, cnts);
    k_pool<<<(N_NODES + POOL_CHUNK - 1) / POOL_CHUNK, 256, 0, stream>>>(a2, batch, sums);
    k_final<<<1, 640, 0, stream>>>(sums, cnts, Wf, bf, out);
}

// Round 4
// 844.622 us; speedup vs baseline: 2.3426x; 1.6182x over previous
//
#include <hip/hip_runtime.h>

#define N_NODES   100000
#define N_EDGES   3200000
#define D_IN      128
#define H1F       32
#define H2F       64
#define N_CLASSES 10
#define N_GRAPHS  64

// ---------------- init: zero counters ----------------
__global__ void k_zero(int* degc, int* cnt, int* fpos, float* sums) {
    int i = blockIdx.x * blockDim.x + threadIdx.x;
    if (i < N_NODES) { degc[i] = 0; cnt[i] = 0; fpos[i] = 0; }
    if (i < N_GRAPHS * H2F) sums[i] = 0.f;
}

// deg by row (source), in-degree histogram by col (dest)
__global__ void k_count(const int* __restrict__ row, const int* __restrict__ col,
                        int* degc, int* cnt) {
    int e = blockIdx.x * blockDim.x + threadIdx.x;
    if (e < N_EDGES) {
        atomicAdd(&degc[row[e]], 1);
        atomicAdd(&cnt[col[e]], 1);
    }
}

__global__ void k_dis(const int* __restrict__ degc, float* dis) {
    int i = blockIdx.x * blockDim.x + threadIdx.x;
    if (i < N_NODES) dis[i] = rsqrtf((float)(1 + degc[i]));  // +1 self-loop
}

// ---------------- exclusive scan of cnt -> off ----------------
__global__ __launch_bounds__(256) void k_scan1(const int* __restrict__ cnt,
        int* __restrict__ off, int* __restrict__ bsum) {
    __shared__ int tsum[256];
    int t = threadIdx.x;
    int base = blockIdx.x * 1024 + t * 4;
    int v[4]; int s = 0;
    #pragma unroll
    for (int i = 0; i < 4; ++i) { int idx = base + i; v[i] = (idx < N_NODES) ? cnt[idx] : 0; s += v[i]; }
    tsum[t] = s; __syncthreads();
    for (int ofs = 1; ofs < 256; ofs <<= 1) {
        int val = (t >= ofs) ? tsum[t - ofs] : 0;
        __syncthreads();
        tsum[t] += val;
        __syncthreads();
    }
    int ex = tsum[t] - s;
    if (t == 255) bsum[blockIdx.x] = tsum[255];
    #pragma unroll
    for (int i = 0; i < 4; ++i) { int idx = base + i; if (idx < N_NODES) { off[idx] = ex; ex += v[i]; } }
}

__global__ void k_scan2(int* bsum, int nb) {
    __shared__ int sh[128];
    int t = threadIdx.x;
    int v = (t < nb) ? bsum[t] : 0;
    sh[t] = v; __syncthreads();
    for (int ofs = 1; ofs < 128; ofs <<= 1) {
        int val = (t >= ofs) ? sh[t - ofs] : 0;
        __syncthreads();
        sh[t] += val;
        __syncthreads();
    }
    if (t < nb) bsum[t] = sh[t] - v;  // exclusive
}

__global__ __launch_bounds__(256) void k_scan3(int* off, const int* __restrict__ bsum) {
    int base = blockIdx.x * 1024 + threadIdx.x * 4;
    int b = bsum[blockIdx.x];
    #pragma unroll
    for (int i = 0; i < 4; ++i) { int idx = base + i; if (idx < N_NODES) off[idx] += b; }
    if (blockIdx.x == 0 && threadIdx.x == 0) off[N_NODES] = N_EDGES;
}

// ---------------- CSR fill (sorted by col) ----------------
__global__ void k_fill(const int* __restrict__ row, const int* __restrict__ col,
                       const int* __restrict__ off, int* fpos, int* __restrict__ srcw) {
    int e = blockIdx.x * blockDim.x + threadIdx.x;
    if (e >= N_EDGES) return;
    int c = col[e];
    int p = off[c] + atomicAdd(&fpos[c], 1);
    srcw[p] = row[e];
}

// ---------------- linear layers (epilogue: scale by dis[n]) ----------------
__global__ __launch_bounds__(256) void k_lin1(const float* __restrict__ x,
        const float* __restrict__ W1, const float* __restrict__ b1,
        const float* __restrict__ dis, float* __restrict__ hs1) {
    __shared__ float w1t[D_IN][H1F + 1];
    __shared__ float xs[8][D_IN];
    int tid = threadIdx.x;
    for (int idx = tid; idx < H1F * D_IN; idx += 256) {
        int f = idx >> 7, k = idx & 127;
        w1t[k][f] = W1[idx];
    }
    long long nbase = (long long)blockIdx.x * 8;
    for (int idx = tid; idx < 8 * D_IN; idx += 256) {
        int nn = idx >> 7, k = idx & 127;
        long long n = nbase + nn;
        xs[nn][k] = (n < N_NODES) ? x[n * D_IN + k] : 0.0f;
    }
    __syncthreads();
    int f = tid & 31, sub = tid >> 5;
    long long n = nbase + sub;
    if (n < N_NODES) {
        float acc = 0.f;
        #pragma unroll
        for (int k = 0; k < D_IN; ++k) acc += xs[sub][k] * w1t[k][f];
        hs1[n * H1F + f] = dis[n] * (acc + b1[f]);
    }
}

__global__ __launch_bounds__(256) void k_lin2(const float* __restrict__ a1,
        const float* __restrict__ W2, const float* __restrict__ b2,
        const float* __restrict__ dis, float* __restrict__ hs2) {
    __shared__ float w2t[H1F][H2F + 1];
    __shared__ float as[4][H1F];
    int tid = threadIdx.x;
    for (int idx = tid; idx < H2F * H1F; idx += 256) {
        int fo = idx >> 5, k = idx & 31;
        w2t[k][fo] = W2[idx];
    }
    long long nbase = (long long)blockIdx.x * 4;
    for (int idx = tid; idx < 4 * H1F; idx += 256) {
        int nn = idx >> 5, k = idx & 31;
        long long n = nbase + nn;
        as[nn][k] = (n < N_NODES) ? fmaxf(a1[n * H1F + k], 0.f) : 0.f;
    }
    __syncthreads();
    int f = tid & 63, sub = tid >> 6;
    long long n = nbase + sub;
    if (n < N_NODES) {
        float acc = 0.f;
        #pragma unroll
        for (int k = 0; k < H1F; ++k) acc += as[sub][k] * w2t[k][f];
        hs2[n * H2F + f] = dis[n] * (acc + b2[f]);
    }
}

// ---------------- gather (SpMM, CSR by destination) ----------------
// a[c][f] = dis[c] * ( hs[c][f] + sum_{j in in(c)} hs[src_j][f] )
// F=32: one wave per node, 4 edges in flight (2 halves x 2 accumulators)
__global__ __launch_bounds__(256) void k_gather32(const int* __restrict__ srcw,
        const int* __restrict__ off, const float* __restrict__ dis,
        const float* __restrict__ hs, float* __restrict__ a) {
    int lane = threadIdx.x & 63;
    int c = (blockIdx.x * 256 + threadIdx.x) >> 6;
    if (c >= N_NODES) return;
    int f = lane & 31, half = lane >> 5;
    int s = off[c], e = off[c + 1];
    float acc0 = half ? 0.f : hs[c * H1F + f];
    float acc1 = 0.f;
    int j = s + half;
    for (; j + 2 < e; j += 4) {
        int s0 = srcw[j], s1 = srcw[j + 2];
        acc0 += hs[s0 * H1F + f];
        acc1 += hs[s1 * H1F + f];
    }
    if (j < e) acc0 += hs[srcw[j] * H1F + f];
    acc0 += acc1;
    acc0 += __shfl_xor(acc0, 32);
    if (half == 0) a[c * H1F + f] = dis[c] * acc0;
}

// F=64: one wave per node, 4 independent accumulators for MLP
__global__ __launch_bounds__(256) void k_gather64(const int* __restrict__ srcw,
        const int* __restrict__ off, const float* __restrict__ dis,
        const float* __restrict__ hs, float* __restrict__ a) {
    int lane = threadIdx.x & 63;
    int c = (blockIdx.x * 256 + threadIdx.x) >> 6;
    if (c >= N_NODES) return;
    int s = off[c], e = off[c + 1];
    float acc0 = hs[c * H2F + lane], acc1 = 0.f, acc2 = 0.f, acc3 = 0.f;
    int j = s;
    for (; j + 3 < e; j += 4) {
        int s0 = srcw[j], s1 = srcw[j + 1], s2 = srcw[j + 2], s3 = srcw[j + 3];
        acc0 += hs[s0 * H2F + lane];
        acc1 += hs[s1 * H2F + lane];
        acc2 += hs[s2 * H2F + lane];
        acc3 += hs[s3 * H2F + lane];
    }
    for (; j < e; ++j) acc0 += hs[srcw[j] * H2F + lane];
    a[c * H2F + lane] = dis[c] * ((acc0 + acc1) + (acc2 + acc3));
}

// ---------------- pooling ----------------
// counts via binary search on sorted batch (no atomics)
__global__ void k_counts_bs(const int* __restrict__ batch, float* counts) {
    int g = threadIdx.x;
    if (g >= N_GRAPHS) return;
    int lo = 0, hi = N_NODES;
    while (lo < hi) { int mid = (lo + hi) >> 1; if (batch[mid] < g) lo = mid + 1; else hi = mid; }
    int start = lo;
    hi = N_NODES;
    while (lo < hi) { int mid = (lo + hi) >> 1; if (batch[mid] < g + 1) lo = mid + 1; else hi = mid; }
    counts[g] = (float)(lo - start);
}

#define POOL_CHUNK 256
__global__ __launch_bounds__(256) void k_pool(const float* __restrict__ a2,
        const int* __restrict__ batch, float* __restrict__ sums) {
    int f = threadIdx.x & 63, sub = threadIdx.x >> 6;
    long long n0 = (long long)blockIdx.x * POOL_CHUNK;
    float acc = 0.f; int gcur = -1;
    for (int i = sub; i < POOL_CHUNK; i += 4) {
        long long n = n0 + i;
        if (n >= N_NODES) break;
        int g = batch[n];
        if (g != gcur) {
            if (gcur >= 0) atomicAdd(&sums[gcur * H2F + f], acc);
            acc = 0.f; gcur = g;
        }
        acc += fmaxf(a2[n * H2F + f], 0.f);   // relu(conv2 out)
    }
    if (gcur >= 0) atomicAdd(&sums[gcur * H2F + f], acc);
}

// ---------------- final: mean, linear, softmax ----------------
__global__ __launch_bounds__(1024) void k_final(const float* __restrict__ sums,
        const float* __restrict__ counts, const float* __restrict__ Wf,
        const float* __restrict__ bf, float* __restrict__ out) {
    __shared__ float l[N_GRAPHS * N_CLASSES];
    int tid = threadIdx.x;
    if (tid < N_GRAPHS * N_CLASSES) {
        int g = tid / N_CLASSES, c = tid % N_CLASSES;
        float cnt = fmaxf(counts[g], 1.0f);
        float acc = bf[c];
        for (int f = 0; f < H2F; ++f)
            acc += (sums[g * H2F + f] / cnt) * Wf[c * H2F + f];
        l[tid] = acc;
    }
    __syncthreads();
    if (tid < N_GRAPHS) {
        float m = -1e30f;
        for (int c = 0; c < N_CLASSES; ++c) m = fmaxf(m, l[tid * N_CLASSES + c]);
        float s = 0.f;
        float ex[N_CLASSES];
        for (int c = 0; c < N_CLASSES; ++c) { ex[c] = expf(l[tid * N_CLASSES + c] - m); s += ex[c]; }
        for (int c = 0; c < N_CLASSES; ++c) out[tid * N_CLASSES + c] = ex[c] / s;
    }
}

extern "C" void kernel_launch(void* const* d_in, const int* in_sizes, int n_in,
                              void* d_out, int out_size, void* d_ws, size_t ws_size,
                              hipStream_t stream) {
    const float* x     = (const float*)d_in[0];
    const int*   ei    = (const int*)d_in[1];
    const int*   batch = (const int*)d_in[2];
    const float* W1    = (const float*)d_in[3];
    const float* b1    = (const float*)d_in[4];
    const float* W2    = (const float*)d_in[5];
    const float* b2    = (const float*)d_in[6];
    const float* Wf    = (const float*)d_in[7];
    const float* bf    = (const float*)d_in[8];
    float* out = (float*)d_out;

    const int* row = ei;            // edge_index[0,:] (source)
    const int* col = ei + N_EDGES;  // edge_index[1,:] (dest)

    // workspace layout
    int*   wsi   = (int*)d_ws;
    int*   degc  = wsi;                    // 100000
    int*   cnt   = degc + N_NODES;         // 100000
    int*   fpos  = cnt  + N_NODES;         // 100000
    int*   off   = fpos + N_NODES;         // 100001 (+1 pad)
    int*   bsum  = off  + N_NODES + 2;     // 128
    int*   srcw  = bsum + 128;             // 3200000
    float* dis   = (float*)(srcw + N_EDGES);        // 100000
    float* hs1   = dis + N_NODES;                   // 3.2M
    float* a1    = hs1 + (long long)N_NODES * H1F;  // 3.2M
    float* hs2   = a1  + (long long)N_NODES * H1F;  // 6.4M
    float* a2    = hs1;                             // alias over hs1+a1 (both dead)
    float* sums  = hs2 + (long long)N_NODES * H2F;  // 4096
    float* cnts  = sums + N_GRAPHS * H2F;           // 64
    // total ~66 MB

    const int nb = (N_NODES + 1023) / 1024;  // 98 scan blocks

    // CSR build + normalization
    k_zero<<<(N_NODES + 255) / 256, 256, 0, stream>>>(degc, cnt, fpos, sums);
    k_count<<<(N_EDGES + 255) / 256, 256, 0, stream>>>(row, col, degc, cnt);
    k_dis<<<(N_NODES + 255) / 256, 256, 0, stream>>>(degc, dis);
    k_scan1<<<nb, 256, 0, stream>>>(cnt, off, bsum);
    k_scan2<<<1, 128, 0, stream>>>(bsum, nb);
    k_scan3<<<nb, 256, 0, stream>>>(off, bsum);
    k_fill<<<(N_EDGES + 255) / 256, 256, 0, stream>>>(row, col, off, fpos, srcw);

    // layer 1
    k_lin1<<<(N_NODES + 7) / 8, 256, 0, stream>>>(x, W1, b1, dis, hs1);
    k_gather32<<<(N_NODES * 64 + 255) / 256, 256, 0, stream>>>(srcw, off, dis, hs1, a1);

    // layer 2
    k_lin2<<<(N_NODES + 3) / 4, 256, 0, stream>>>(a1, W2, b2, dis, hs2);
    k_gather64<<<(N_NODES * 64 + 255) / 256, 256, 0, stream>>>(srcw, off, dis, hs2, a2);

    // pooling + head
    k_counts_bs<<<1, 64, 0, stream>>>(batch, cnts);
    k_pool<<<(N_NODES + POOL_CHUNK - 1) / POOL_CHUNK, 256, 0, stream>>>(a2, batch, sums);
    k_final<<<1, 640, 0, stream>>>(sums, cnts, Wf, bf, out);
}

// Round 5
// 545.430 us; speedup vs baseline: 3.6276x; 1.5485x over previous
//
#include <hip/hip_runtime.h>

#define N_NODES   100000
#define N_EDGES   3200000
#define D_IN      128
#define H1F       32
#define H2F       64
#define N_CLASSES 10
#define N_GRAPHS  64

#define NBUCK 391      // ceil(100000 / 256) buckets of 256 nodes
#define NPB   256      // partition blocks
#define EPB   (N_EDGES / NPB)   // 12500 edges per partition block (exact)

// ---------------- tiny zero for bucket counters ----------------
__global__ void k_zero2(int* ccount, int* rcount) {
    int t = threadIdx.x;
    for (int i = t; i < NBUCK; i += 256) { ccount[i] = 0; rcount[i] = 0; }
}

// ---------------- pass 1: coarse bucket histograms (col and row) ----------------
__global__ __launch_bounds__(256) void k_coarse(const int* __restrict__ row,
        const int* __restrict__ col, int* ccount, int* rcount) {
    __shared__ int ch[NBUCK], rh[NBUCK];
    int t = threadIdx.x;
    for (int i = t; i < NBUCK; i += 256) { ch[i] = 0; rh[i] = 0; }
    __syncthreads();
    int s = blockIdx.x * EPB, e = s + EPB;
    for (int i = s + t; i < e; i += 256) {
        atomicAdd(&ch[col[i] >> 8], 1);
        atomicAdd(&rh[row[i] >> 8], 1);
    }
    __syncthreads();
    for (int i = t; i < NBUCK; i += 256) {
        if (ch[i]) atomicAdd(&ccount[i], ch[i]);
        if (rh[i]) atomicAdd(&rcount[i], rh[i]);
    }
}

// ---------------- pass 2: scan bucket counts -> offsets; misc init ----------------
__global__ __launch_bounds__(512) void k_cscan(const int* __restrict__ ccount,
        const int* __restrict__ rcount, int* coff, int* roff, int* cpos, int* rpos,
        float* sums, int* off) {
    __shared__ int sc[512], sr[512];
    int t = threadIdx.x;
    int vc = (t < NBUCK) ? ccount[t] : 0;
    int vr = (t < NBUCK) ? rcount[t] : 0;
    sc[t] = vc; sr[t] = vr; __syncthreads();
    for (int o = 1; o < 512; o <<= 1) {
        int a = (t >= o) ? sc[t - o] : 0;
        int b = (t >= o) ? sr[t - o] : 0;
        __syncthreads();
        sc[t] += a; sr[t] += b;
        __syncthreads();
    }
    if (t < NBUCK) {
        int ce = sc[t] - vc, re = sr[t] - vr;
        coff[t] = ce; cpos[t] = ce;
        roff[t] = re; rpos[t] = re;
    }
    if (t == 0) { coff[NBUCK] = N_EDGES; roff[NBUCK] = N_EDGES; off[N_NODES] = N_EDGES; }
    for (int i = t; i < N_GRAPHS * H2F; i += 512) sums[i] = 0.f;
}

// ---------------- pass 3: partition (col,row) pairs by col>>8 ----------------
__global__ __launch_bounds__(256) void k_part_col(const int* __restrict__ row,
        const int* __restrict__ col, int* cpos, unsigned long long* __restrict__ partc) {
    __shared__ int h[NBUCK], base[NBUCK], run[NBUCK];
    int t = threadIdx.x;
    for (int i = t; i < NBUCK; i += 256) { h[i] = 0; run[i] = 0; }
    __syncthreads();
    int s = blockIdx.x * EPB, e = s + EPB;
    for (int i = s + t; i < e; i += 256) atomicAdd(&h[col[i] >> 8], 1);
    __syncthreads();
    for (int i = t; i < NBUCK; i += 256)
        base[i] = h[i] ? atomicAdd(&cpos[i], h[i]) : 0;
    __syncthreads();
    for (int i = s + t; i < e; i += 256) {
        int c = col[i];
        int b = c >> 8;
        int r = atomicAdd(&run[b], 1);
        partc[base[b] + r] = ((unsigned long long)(unsigned)c << 32) | (unsigned)row[i];
    }
}

// ---------------- pass 4: partition row values by row>>8 ----------------
__global__ __launch_bounds__(256) void k_part_row(const int* __restrict__ row,
        int* rpos, int* __restrict__ partr) {
    __shared__ int h[NBUCK], base[NBUCK], run[NBUCK];
    int t = threadIdx.x;
    for (int i = t; i < NBUCK; i += 256) { h[i] = 0; run[i] = 0; }
    __syncthreads();
    int s = blockIdx.x * EPB, e = s + EPB;
    for (int i = s + t; i < e; i += 256) atomicAdd(&h[row[i] >> 8], 1);
    __syncthreads();
    for (int i = t; i < NBUCK; i += 256)
        base[i] = h[i] ? atomicAdd(&rpos[i], h[i]) : 0;
    __syncthreads();
    for (int i = s + t; i < e; i += 256) {
        int v = row[i];
        int b = v >> 8;
        int r = atomicAdd(&run[b], 1);
        partr[base[b] + r] = v;
    }
}

// ---------------- pass 5: per-bucket CSR (off + srcw), all in LDS ----------------
__global__ __launch_bounds__(256) void k_bucket_col(const unsigned long long* __restrict__ partc,
        const int* __restrict__ coff, int* __restrict__ off, int* __restrict__ srcw) {
    __shared__ int cnt[256], sc[256], run[256];
    int b = blockIdx.x, t = threadIdx.x;
    cnt[t] = 0; run[t] = 0;
    __syncthreads();
    int s = coff[b], e = coff[b + 1];
    for (int i = s + t; i < e; i += 256) {
        int c = (int)(partc[i] >> 32);
        atomicAdd(&cnt[c & 255], 1);
    }
    __syncthreads();
    int v = cnt[t]; sc[t] = v; __syncthreads();
    for (int o = 1; o < 256; o <<= 1) {
        int a = (t >= o) ? sc[t - o] : 0;
        __syncthreads();
        sc[t] += a;
        __syncthreads();
    }
    int ex = sc[t] - v;          // exclusive scan
    __syncthreads();
    sc[t] = ex;                  // sc := local offsets
    __syncthreads();
    int n = (b << 8) + t;
    if (n < N_NODES) off[n] = s + ex;
    for (int i = s + t; i < e; i += 256) {
        unsigned long long p = partc[i];
        int c = ((int)(p >> 32)) & 255;
        int r = atomicAdd(&run[c], 1);
        srcw[s + sc[c] + r] = (int)(p & 0xffffffffu);
    }
}

// ---------------- pass 6: per-bucket out-degree histogram -> dis ----------------
__global__ __launch_bounds__(256) void k_bucket_row(const int* __restrict__ partr,
        const int* __restrict__ roff, float* __restrict__ dis) {
    __shared__ int cnt[256];
    int b = blockIdx.x, t = threadIdx.x;
    cnt[t] = 0;
    __syncthreads();
    int s = roff[b], e = roff[b + 1];
    for (int i = s + t; i < e; i += 256) atomicAdd(&cnt[partr[i] & 255], 1);
    __syncthreads();
    int n = (b << 8) + t;
    if (n < N_NODES) dis[n] = rsqrtf((float)(1 + cnt[t]));  // +1 self-loop
}

// ---------------- linear layers (epilogue: scale by dis[n]) ----------------
__global__ __launch_bounds__(256) void k_lin1(const float* __restrict__ x,
        const float* __restrict__ W1, const float* __restrict__ b1,
        const float* __restrict__ dis, float* __restrict__ hs1) {
    __shared__ float w1t[D_IN][H1F + 1];
    __shared__ float xs[8][D_IN];
    int tid = threadIdx.x;
    for (int idx = tid; idx < H1F * D_IN; idx += 256) {
        int f = idx >> 7, k = idx & 127;
        w1t[k][f] = W1[idx];
    }
    long long nbase = (long long)blockIdx.x * 8;
    for (int idx = tid; idx < 8 * D_IN; idx += 256) {
        int nn = idx >> 7, k = idx & 127;
        long long n = nbase + nn;
        xs[nn][k] = (n < N_NODES) ? x[n * D_IN + k] : 0.0f;
    }
    __syncthreads();
    int f = tid & 31, sub = tid >> 5;
    long long n = nbase + sub;
    if (n < N_NODES) {
        float acc = 0.f;
        #pragma unroll
        for (int k = 0; k < D_IN; ++k) acc += xs[sub][k] * w1t[k][f];
        hs1[n * H1F + f] = dis[n] * (acc + b1[f]);
    }
}

__global__ __launch_bounds__(256) void k_lin2(const float* __restrict__ a1,
        const float* __restrict__ W2, const float* __restrict__ b2,
        const float* __restrict__ dis, float* __restrict__ hs2) {
    __shared__ float w2t[H1F][H2F + 1];
    __shared__ float as[4][H1F];
    int tid = threadIdx.x;
    for (int idx = tid; idx < H2F * H1F; idx += 256) {
        int fo = idx >> 5, k = idx & 31;
        w2t[k][fo] = W2[idx];
    }
    long long nbase = (long long)blockIdx.x * 4;
    for (int idx = tid; idx < 4 * H1F; idx += 256) {
        int nn = idx >> 5, k = idx & 31;
        long long n = nbase + nn;
        as[nn][k] = (n < N_NODES) ? fmaxf(a1[n * H1F + k], 0.f) : 0.f;
    }
    __syncthreads();
    int f = tid & 63, sub = tid >> 6;
    long long n = nbase + sub;
    if (n < N_NODES) {
        float acc = 0.f;
        #pragma unroll
        for (int k = 0; k < H1F; ++k) acc += as[sub][k] * w2t[k][f];
        hs2[n * H2F + f] = dis[n] * (acc + b2[f]);
    }
}

// ---------------- gather (SpMM, CSR by destination) ----------------
__global__ __launch_bounds__(256) void k_gather32(const int* __restrict__ srcw,
        const int* __restrict__ off, const float* __restrict__ dis,
        const float* __restrict__ hs, float* __restrict__ a) {
    int lane = threadIdx.x & 63;
    int c = (blockIdx.x * 256 + threadIdx.x) >> 6;
    if (c >= N_NODES) return;
    int f = lane & 31, half = lane >> 5;
    int s = off[c], e = off[c + 1];
    float acc0 = half ? 0.f : hs[c * H1F + f];
    float acc1 = 0.f;
    int j = s + half;
    for (; j + 2 < e; j += 4) {
        int s0 = srcw[j], s1 = srcw[j + 2];
        acc0 += hs[s0 * H1F + f];
        acc1 += hs[s1 * H1F + f];
    }
    if (j < e) acc0 += hs[srcw[j] * H1F + f];
    acc0 += acc1;
    acc0 += __shfl_xor(acc0, 32);
    if (half == 0) a[c * H1F + f] = dis[c] * acc0;
}

__global__ __launch_bounds__(256) void k_gather64(const int* __restrict__ srcw,
        const int* __restrict__ off, const float* __restrict__ dis,
        const float* __restrict__ hs, float* __restrict__ a) {
    int lane = threadIdx.x & 63;
    int c = (blockIdx.x * 256 + threadIdx.x) >> 6;
    if (c >= N_NODES) return;
    int s = off[c], e = off[c + 1];
    float acc0 = hs[c * H2F + lane], acc1 = 0.f, acc2 = 0.f, acc3 = 0.f;
    int j = s;
    for (; j + 3 < e; j += 4) {
        int s0 = srcw[j], s1 = srcw[j + 1], s2 = srcw[j + 2], s3 = srcw[j + 3];
        acc0 += hs[s0 * H2F + lane];
        acc1 += hs[s1 * H2F + lane];
        acc2 += hs[s2 * H2F + lane];
        acc3 += hs[s3 * H2F + lane];
    }
    for (; j < e; ++j) acc0 += hs[srcw[j] * H2F + lane];
    a[c * H2F + lane] = dis[c] * ((acc0 + acc1) + (acc2 + acc3));
}

// ---------------- pooling ----------------
__global__ void k_counts_bs(const int* __restrict__ batch, float* counts) {
    int g = threadIdx.x;
    if (g >= N_GRAPHS) return;
    int lo = 0, hi = N_NODES;
    while (lo < hi) { int mid = (lo + hi) >> 1; if (batch[mid] < g) lo = mid + 1; else hi = mid; }
    int start = lo;
    hi = N_NODES;
    while (lo < hi) { int mid = (lo + hi) >> 1; if (batch[mid] < g + 1) lo = mid + 1; else hi = mid; }
    counts[g] = (float)(lo - start);
}

#define POOL_CHUNK 256
__global__ __launch_bounds__(256) void k_pool(const float* __restrict__ a2,
        const int* __restrict__ batch, float* __restrict__ sums) {
    int f = threadIdx.x & 63, sub = threadIdx.x >> 6;
    long long n0 = (long long)blockIdx.x * POOL_CHUNK;
    float acc = 0.f; int gcur = -1;
    for (int i = sub; i < POOL_CHUNK; i += 4) {
        long long n = n0 + i;
        if (n >= N_NODES) break;
        int g = batch[n];
        if (g != gcur) {
            if (gcur >= 0) atomicAdd(&sums[gcur * H2F + f], acc);
            acc = 0.f; gcur = g;
        }
        acc += fmaxf(a2[n * H2F + f], 0.f);   // relu(conv2 out)
    }
    if (gcur >= 0) atomicAdd(&sums[gcur * H2F + f], acc);
}

// ---------------- final: mean, linear, softmax ----------------
__global__ __launch_bounds__(1024) void k_final(const float* __restrict__ sums,
        const float* __restrict__ counts, const float* __restrict__ Wf,
        const float* __restrict__ bf, float* __restrict__ out) {
    __shared__ float l[N_GRAPHS * N_CLASSES];
    int tid = threadIdx.x;
    if (tid < N_GRAPHS * N_CLASSES) {
        int g = tid / N_CLASSES, c = tid % N_CLASSES;
        float cnt = fmaxf(counts[g], 1.0f);
        float acc = bf[c];
        for (int f = 0; f < H2F; ++f)
            acc += (sums[g * H2F + f] / cnt) * Wf[c * H2F + f];
        l[tid] = acc;
    }
    __syncthreads();
    if (tid < N_GRAPHS) {
        float m = -1e30f;
        for (int c = 0; c < N_CLASSES; ++c) m = fmaxf(m, l[tid * N_CLASSES + c]);
        float s = 0.f;
        float ex[N_CLASSES];
        for (int c = 0; c < N_CLASSES; ++c) { ex[c] = expf(l[tid * N_CLASSES + c] - m); s += ex[c]; }
        for (int c = 0; c < N_CLASSES; ++c) out[tid * N_CLASSES + c] = ex[c] / s;
    }
}

extern "C" void kernel_launch(void* const* d_in, const int* in_sizes, int n_in,
                              void* d_out, int out_size, void* d_ws, size_t ws_size,
                              hipStream_t stream) {
    const float* x     = (const float*)d_in[0];
    const int*   ei    = (const int*)d_in[1];
    const int*   batch = (const int*)d_in[2];
    const float* W1    = (const float*)d_in[3];
    const float* b1    = (const float*)d_in[4];
    const float* W2    = (const float*)d_in[5];
    const float* b2    = (const float*)d_in[6];
    const float* Wf    = (const float*)d_in[7];
    const float* bf    = (const float*)d_in[8];
    float* out = (float*)d_out;

    const int* row = ei;            // edge_index[0,:] (source)
    const int* col = ei + N_EDGES;  // edge_index[1,:] (dest)

    // workspace layout (int units)
    int* W = (int*)d_ws;
    int*   ccount = W + 0;          // 391  (pad to 400)
    int*   rcount = W + 400;        // 391
    int*   coff   = W + 800;        // 392
    int*   roff   = W + 1200;       // 392
    int*   cpos   = W + 1600;       // 391
    int*   rpos   = W + 2000;       // 391
    int*   off    = W + 2400;       // 100001 -> pad to 102408
    int*   srcw   = W + 102408;     // 3.2M  -> 3302408 (8B aligned: 3302408*4 % 8 == 0)
    unsigned long long* partc = (unsigned long long*)(W + 3302408);  // 3.2M u64 = 6.4M ints
    float* hs2    = (float*)(W + 3302408);                // alias partc (dead before lin2)
    int*   partr  = W + 9702408;    // 3.2M
    float* hs1    = (float*)(W + 9702408);                // alias partr (dead before lin1)
    float* a1     = (float*)(W + 12902408);               // 3.2M
    float* a2     = (float*)(W + 9702408);                // alias [hs1|a1] (6.4M, dead before gather64)
    float* dis    = (float*)(W + 16102408);               // 100000
    float* sums   = (float*)(W + 16202408);               // 4096
    float* cnts   = (float*)(W + 16206504);               // 64
    // total ~64.8 MB

    // ---- CSR build via 2-pass radix partition ----
    k_zero2<<<1, 256, 0, stream>>>(ccount, rcount);
    k_coarse<<<NPB, 256, 0, stream>>>(row, col, ccount, rcount);
    k_cscan<<<1, 512, 0, stream>>>(ccount, rcount, coff, roff, cpos, rpos, sums, off);
    k_part_col<<<NPB, 256, 0, stream>>>(row, col, cpos, partc);
    k_part_row<<<NPB, 256, 0, stream>>>(row, rpos, partr);
    k_bucket_col<<<NBUCK, 256, 0, stream>>>(partc, coff, off, srcw);
    k_bucket_row<<<NBUCK, 256, 0, stream>>>(partr, roff, dis);

    // ---- layer 1 ----
    k_lin1<<<(N_NODES + 7) / 8, 256, 0, stream>>>(x, W1, b1, dis, hs1);
    k_gather32<<<(N_NODES * 64 + 255) / 256, 256, 0, stream>>>(srcw, off, dis, hs1, a1);

    // ---- layer 2 ----
    k_lin2<<<(N_NODES + 3) / 4, 256, 0, stream>>>(a1, W2, b2, dis, hs2);
    k_gather64<<<(N_NODES * 64 + 255) / 256, 256, 0, stream>>>(srcw, off, dis, hs2, a2);

    // ---- pooling + head ----
    k_counts_bs<<<1, 64, 0, stream>>>(batch, cnts);
    k_pool<<<(N_NODES + POOL_CHUNK - 1) / POOL_CHUNK, 256, 0, stream>>>(a2, batch, sums);
    k_final<<<1, 640, 0, stream>>>(sums, cnts, Wf, bf, out);
}

// Round 6
// 374.996 us; speedup vs baseline: 5.2763x; 1.4545x over previous
//
#include <hip/hip_runtime.h>

#define N_NODES   100000
#define N_EDGES   3200000
#define D_IN      128
#define H1F       32
#define H2F       64
#define N_CLASSES 10
#define N_GRAPHS  64

#define NBUCK 391      // ceil(100000 / 256) buckets of 256 nodes
#define NPB   256      // partition blocks
#define EPB   (N_EDGES / NPB)   // 12500 edges per partition block (exact)

// bf16 helpers (RNE pack)
__device__ __forceinline__ unsigned f2bf(float f) {
    unsigned u = __float_as_uint(f);
    return (u + 0x7fffu + ((u >> 16) & 1u)) >> 16;
}
__device__ __forceinline__ float bf2f(unsigned h) {
    return __uint_as_float(h << 16);
}

// ---------------- tiny zero for bucket counters ----------------
__global__ void k_zero2(int* ccount, int* rcount) {
    int t = threadIdx.x;
    for (int i = t; i < NBUCK; i += 256) { ccount[i] = 0; rcount[i] = 0; }
}

// ---------------- pass 1: coarse bucket histograms (col and row) ----------------
__global__ __launch_bounds__(256) void k_coarse(const int* __restrict__ row,
        const int* __restrict__ col, int* ccount, int* rcount) {
    __shared__ int ch[NBUCK], rh[NBUCK];
    int t = threadIdx.x;
    for (int i = t; i < NBUCK; i += 256) { ch[i] = 0; rh[i] = 0; }
    __syncthreads();
    int s = blockIdx.x * EPB, e = s + EPB;
    for (int i = s + t; i < e; i += 256) {
        atomicAdd(&ch[col[i] >> 8], 1);
        atomicAdd(&rh[row[i] >> 8], 1);
    }
    __syncthreads();
    for (int i = t; i < NBUCK; i += 256) {
        if (ch[i]) atomicAdd(&ccount[i], ch[i]);
        if (rh[i]) atomicAdd(&rcount[i], rh[i]);
    }
}

// ---------------- pass 2: scan bucket counts -> offsets; misc init ----------------
__global__ __launch_bounds__(512) void k_cscan(const int* __restrict__ ccount,
        const int* __restrict__ rcount, int* coff, int* roff, int* cpos, int* rpos,
        float* sums, int* off) {
    __shared__ int sc[512], sr[512];
    int t = threadIdx.x;
    int vc = (t < NBUCK) ? ccount[t] : 0;
    int vr = (t < NBUCK) ? rcount[t] : 0;
    sc[t] = vc; sr[t] = vr; __syncthreads();
    for (int o = 1; o < 512; o <<= 1) {
        int a = (t >= o) ? sc[t - o] : 0;
        int b = (t >= o) ? sr[t - o] : 0;
        __syncthreads();
        sc[t] += a; sr[t] += b;
        __syncthreads();
    }
    if (t < NBUCK) {
        int ce = sc[t] - vc, re = sr[t] - vr;
        coff[t] = ce; cpos[t] = ce;
        roff[t] = re; rpos[t] = re;
    }
    if (t == 0) { coff[NBUCK] = N_EDGES; roff[NBUCK] = N_EDGES; off[N_NODES] = N_EDGES; }
    for (int i = t; i < N_GRAPHS * H2F; i += 512) sums[i] = 0.f;
}

// ---------------- pass 3: single-pass partition (col-keyed pairs, row values) ----------------
__global__ __launch_bounds__(256) void k_part(const int* __restrict__ row,
        const int* __restrict__ col, int* cpos, int* rpos,
        unsigned* __restrict__ partc, int* __restrict__ partr) {
    __shared__ int hc[NBUCK], bc[NBUCK], kc[NBUCK];
    __shared__ int hr[NBUCK], br[NBUCK], kr[NBUCK];
    int t = threadIdx.x;
    for (int i = t; i < NBUCK; i += 256) { hc[i] = 0; kc[i] = 0; hr[i] = 0; kr[i] = 0; }
    __syncthreads();
    int s = blockIdx.x * EPB, e = s + EPB;
    for (int i = s + t; i < e; i += 256) {
        atomicAdd(&hc[col[i] >> 8], 1);
        atomicAdd(&hr[row[i] >> 8], 1);
    }
    __syncthreads();
    for (int i = t; i < NBUCK; i += 256) {
        bc[i] = hc[i] ? atomicAdd(&cpos[i], hc[i]) : 0;
        br[i] = hr[i] ? atomicAdd(&rpos[i], hr[i]) : 0;
    }
    __syncthreads();
    for (int i = s + t; i < e; i += 256) {
        int c = col[i], r = row[i];
        int b = c >> 8;
        int k = atomicAdd(&kc[b], 1);
        partc[bc[b] + k] = ((unsigned)(c & 255) << 17) | (unsigned)r;  // row < 2^17
        int b2_ = r >> 8;
        int k2 = atomicAdd(&kr[b2_], 1);
        partr[br[b2_] + k2] = r;
    }
}

// ---------------- pass 4: per-bucket CSR (off + srcw), all in LDS ----------------
__global__ __launch_bounds__(256) void k_bucket_col(const unsigned* __restrict__ partc,
        const int* __restrict__ coff, int* __restrict__ off, int* __restrict__ srcw) {
    __shared__ int cnt[256], sc[256], run[256];
    int b = blockIdx.x, t = threadIdx.x;
    cnt[t] = 0; run[t] = 0;
    __syncthreads();
    int s = coff[b], e = coff[b + 1];
    for (int i = s + t; i < e; i += 256)
        atomicAdd(&cnt[partc[i] >> 17], 1);
    __syncthreads();
    int v = cnt[t]; sc[t] = v; __syncthreads();
    for (int o = 1; o < 256; o <<= 1) {
        int a = (t >= o) ? sc[t - o] : 0;
        __syncthreads();
        sc[t] += a;
        __syncthreads();
    }
    int ex = sc[t] - v;
    __syncthreads();
    sc[t] = ex;
    __syncthreads();
    int n = (b << 8) + t;
    if (n < N_NODES) off[n] = s + ex;
    for (int i = s + t; i < e; i += 256) {
        unsigned p = partc[i];
        int c = p >> 17;
        int k = atomicAdd(&run[c], 1);
        srcw[s + sc[c] + k] = (int)(p & 0x1FFFFu);
    }
}

// ---------------- pass 5: per-bucket out-degree histogram -> dis ----------------
__global__ __launch_bounds__(256) void k_bucket_row(const int* __restrict__ partr,
        const int* __restrict__ roff, float* __restrict__ dis) {
    __shared__ int cnt[256];
    int b = blockIdx.x, t = threadIdx.x;
    cnt[t] = 0;
    __syncthreads();
    int s = roff[b], e = roff[b + 1];
    for (int i = s + t; i < e; i += 256) atomicAdd(&cnt[partr[i] & 255], 1);
    __syncthreads();
    int n = (b << 8) + t;
    if (n < N_NODES) dis[n] = rsqrtf((float)(1 + cnt[t]));  // +1 self-loop
}

// ---------------- lin1: hs1b = bf16( dis[n] * (x W1^T + b1) ) ----------------
__global__ __launch_bounds__(256) void k_lin1(const float* __restrict__ x,
        const float* __restrict__ W1, const float* __restrict__ b1,
        const float* __restrict__ dis, unsigned* __restrict__ hs1b) {
    __shared__ float w1t[D_IN][H1F + 1];
    __shared__ float xs[8][D_IN];
    int tid = threadIdx.x;
    for (int idx = tid; idx < H1F * D_IN; idx += 256) {
        int f = idx >> 7, k = idx & 127;
        w1t[k][f] = W1[idx];
    }
    int nbase = blockIdx.x * 8;
    for (int idx = tid; idx < 8 * D_IN; idx += 256) {
        int nn = idx >> 7, k = idx & 127;
        int n = nbase + nn;
        xs[nn][k] = (n < N_NODES) ? x[(long long)n * D_IN + k] : 0.0f;
    }
    __syncthreads();
    int f = tid & 31, sub = tid >> 5;
    int n = nbase + sub;
    float acc = 0.f;
    #pragma unroll
    for (int k = 0; k < D_IN; ++k) acc += xs[sub][k] * w1t[k][f];
    float val = (n < N_NODES) ? dis[n] * (acc + b1[f]) : 0.f;
    float other = __shfl_xor(val, 1);
    if ((f & 1) == 0 && n < N_NODES)
        hs1b[n * 16 + (f >> 1)] = f2bf(val) | (f2bf(other) << 16);
}

// ---------------- gather1: hs2b = bf16( dis_c * relu( dis_c*(hs1_c + sum hs1_src) ) ) ----
// one wave per node; 4 groups of 16 lanes, each group one edge (64B row), lane = 2 feats
__global__ __launch_bounds__(256) void k_gather1(const int* __restrict__ srcw,
        const int* __restrict__ off, const float* __restrict__ dis,
        const unsigned* __restrict__ hs, unsigned* __restrict__ out) {
    int lane = threadIdx.x & 63;
    int c = (blockIdx.x * 256 + threadIdx.x) >> 6;
    if (c >= N_NODES) return;
    int g = lane >> 4, lf = lane & 15;
    int s = off[c], e = off[c + 1];
    float a0 = 0.f, a1 = 0.f;
    if (g == 0) {
        unsigned su = hs[c * 16 + lf];
        a0 = bf2f(su & 0xffffu); a1 = bf2f(su >> 16);
    }
    int j = s + g;
    for (; j + 4 < e; j += 8) {
        int s0 = srcw[j], s1 = srcw[j + 4];
        unsigned u0 = hs[s0 * 16 + lf];
        unsigned u1 = hs[s1 * 16 + lf];
        a0 += bf2f(u0 & 0xffffu); a1 += bf2f(u0 >> 16);
        a0 += bf2f(u1 & 0xffffu); a1 += bf2f(u1 >> 16);
    }
    if (j < e) {
        unsigned u0 = hs[srcw[j] * 16 + lf];
        a0 += bf2f(u0 & 0xffffu); a1 += bf2f(u0 >> 16);
    }
    a0 += __shfl_xor(a0, 16); a0 += __shfl_xor(a0, 32);
    a1 += __shfl_xor(a1, 16); a1 += __shfl_xor(a1, 32);
    if (g == 0) {
        float dc = dis[c];
        float v0 = dc * fmaxf(dc * a0, 0.f);
        float v1 = dc * fmaxf(dc * a1, 0.f);
        out[c * 16 + lf] = f2bf(v0) | (f2bf(v1) << 16);
    }
}

// ---------------- gather2: G = dis_c*(hs2_c + sum hs2_src) [32 fp32], Sd = dis_c*(dis_c+sum dis_src)
__global__ __launch_bounds__(256) void k_gather2(const int* __restrict__ srcw,
        const int* __restrict__ off, const float* __restrict__ dis,
        const unsigned* __restrict__ hs, float* __restrict__ G,
        float* __restrict__ Sd) {
    int lane = threadIdx.x & 63;
    int c = (blockIdx.x * 256 + threadIdx.x) >> 6;
    if (c >= N_NODES) return;
    int g = lane >> 4, lf = lane & 15;
    int s = off[c], e = off[c + 1];
    float a0 = 0.f, a1 = 0.f, ad = 0.f;
    if (g == 0) {
        unsigned su = hs[c * 16 + lf];
        a0 = bf2f(su & 0xffffu); a1 = bf2f(su >> 16);
    }
    int j = s + g;
    for (; j + 4 < e; j += 8) {
        int s0 = srcw[j], s1 = srcw[j + 4];
        unsigned u0 = hs[s0 * 16 + lf];
        unsigned u1 = hs[s1 * 16 + lf];
        ad += dis[s0] + dis[s1];
        a0 += bf2f(u0 & 0xffffu); a1 += bf2f(u0 >> 16);
        a0 += bf2f(u1 & 0xffffu); a1 += bf2f(u1 >> 16);
    }
    if (j < e) {
        int s0 = srcw[j];
        unsigned u0 = hs[s0 * 16 + lf];
        ad += dis[s0];
        a0 += bf2f(u0 & 0xffffu); a1 += bf2f(u0 >> 16);
    }
    a0 += __shfl_xor(a0, 16); a0 += __shfl_xor(a0, 32);
    a1 += __shfl_xor(a1, 16); a1 += __shfl_xor(a1, 32);
    ad += __shfl_xor(ad, 16); ad += __shfl_xor(ad, 32);
    if (g == 0) {
        float dc = dis[c];
        float2 w; w.x = dc * a0; w.y = dc * a1;
        *(float2*)(&G[c * 32 + lf * 2]) = w;
        if (lf == 0) Sd[c] = dc * (dc + ad);
    }
}

// ---------------- counts via binary search on sorted batch ----------------
__global__ void k_counts_bs(const int* __restrict__ batch, float* counts) {
    int g = threadIdx.x;
    if (g >= N_GRAPHS) return;
    int lo = 0, hi = N_NODES;
    while (lo < hi) { int mid = (lo + hi) >> 1; if (batch[mid] < g) lo = mid + 1; else hi = mid; }
    int start = lo;
    hi = N_NODES;
    while (lo < hi) { int mid = (lo + hi) >> 1; if (batch[mid] < g + 1) lo = mid + 1; else hi = mid; }
    counts[g] = (float)(lo - start);
}

// ---------------- fused lin2 + relu + mean-pool accumulate ----------------
// a2[n][f] = relu( G[n]·W2[f][:] + Sd[n]*b2[f] );  sums[batch[n]][f] += a2
__global__ __launch_bounds__(256) void k_lin2pool(const float* __restrict__ G,
        const float* __restrict__ Sd, const float* __restrict__ W2,
        const float* __restrict__ b2, const int* __restrict__ batch,
        float* __restrict__ sums) {
    __shared__ float w2t[H1F][H2F + 1];
    int tid = threadIdx.x;
    for (int idx = tid; idx < H2F * H1F; idx += 256) {
        int fo = idx >> 5, k = idx & 31;
        w2t[k][fo] = W2[idx];
    }
    __syncthreads();
    int f = tid & 63, sub = tid >> 6;
    float bfv = b2[f];
    int n0 = blockIdx.x * 256;
    float acc = 0.f; int gcur = -1;
    for (int i = sub; i < 256; i += 4) {
        int n = n0 + i;
        if (n >= N_NODES) break;
        const float4* Gr = (const float4*)(&G[n * 32]);
        float d = Sd[n] * bfv;
        #pragma unroll
        for (int q = 0; q < 8; ++q) {
            float4 v = Gr[q];
            d += v.x * w2t[4 * q][f] + v.y * w2t[4 * q + 1][f]
               + v.z * w2t[4 * q + 2][f] + v.w * w2t[4 * q + 3][f];
        }
        d = fmaxf(d, 0.f);
        int gg = batch[n];
        if (gg != gcur) {
            if (gcur >= 0) atomicAdd(&sums[gcur * H2F + f], acc);
            acc = 0.f; gcur = gg;
        }
        acc += d;
    }
    if (gcur >= 0) atomicAdd(&sums[gcur * H2F + f], acc);
}

// ---------------- final: mean, linear, softmax ----------------
__global__ __launch_bounds__(1024) void k_final(const float* __restrict__ sums,
        const float* __restrict__ counts, const float* __restrict__ Wf,
        const float* __restrict__ bf, float* __restrict__ out) {
    __shared__ float l[N_GRAPHS * N_CLASSES];
    int tid = threadIdx.x;
    if (tid < N_GRAPHS * N_CLASSES) {
        int g = tid / N_CLASSES, c = tid % N_CLASSES;
        float cnt = fmaxf(counts[g], 1.0f);
        float acc = bf[c];
        for (int f = 0; f < H2F; ++f)
            acc += (sums[g * H2F + f] / cnt) * Wf[c * H2F + f];
        l[tid] = acc;
    }
    __syncthreads();
    if (tid < N_GRAPHS) {
        float m = -1e30f;
        for (int c = 0; c < N_CLASSES; ++c) m = fmaxf(m, l[tid * N_CLASSES + c]);
        float s = 0.f;
        float ex[N_CLASSES];
        for (int c = 0; c < N_CLASSES; ++c) { ex[c] = expf(l[tid * N_CLASSES + c] - m); s += ex[c]; }
        for (int c = 0; c < N_CLASSES; ++c) out[tid * N_CLASSES + c] = ex[c] / s;
    }
}

extern "C" void kernel_launch(void* const* d_in, const int* in_sizes, int n_in,
                              void* d_out, int out_size, void* d_ws, size_t ws_size,
                              hipStream_t stream) {
    const float* x     = (const float*)d_in[0];
    const int*   ei    = (const int*)d_in[1];
    const int*   batch = (const int*)d_in[2];
    const float* W1    = (const float*)d_in[3];
    const float* b1    = (const float*)d_in[4];
    const float* W2    = (const float*)d_in[5];
    const float* b2    = (const float*)d_in[6];
    const float* Wf    = (const float*)d_in[7];
    const float* bf    = (const float*)d_in[8];
    float* out = (float*)d_out;

    const int* row = ei;            // edge_index[0,:] (source)
    const int* col = ei + N_EDGES;  // edge_index[1,:] (dest)

    // workspace layout (int units)
    int* W = (int*)d_ws;
    int*      ccount = W + 0;         // 391 (pad 400)
    int*      rcount = W + 400;
    int*      coff   = W + 800;       // 392
    int*      roff   = W + 1200;
    int*      cpos   = W + 1600;
    int*      rpos   = W + 2000;
    int*      off    = W + 2400;      // 100001 -> next 102408
    int*      srcw   = W + 102408;    // 3.2M -> 3302408
    unsigned* partc  = (unsigned*)(W + 3302408);  // 3.2M u32 -> 6502408
    float*    G      = (float*)(W + 3302408);     // alias partc (dead after bucket_col)
    int*      partr  = W + 6502408;   // 3.2M -> 9702408
    float*    dis    = (float*)(W + 9702408);     // 100000
    float*    Sd     = (float*)(W + 9802408);     // 100000
    unsigned* hs1b   = (unsigned*)(W + 9902408);  // 1.6M u32 -> 11502408
    unsigned* hs2b   = (unsigned*)(W + 11502408); // 1.6M u32 -> 13102408
    float*    sums   = (float*)(W + 13102408);    // 4096
    float*    cnts   = (float*)(W + 13106504);    // 64
    // total ~52.4 MB

    // ---- CSR build via 2-pass radix partition ----
    k_zero2<<<1, 256, 0, stream>>>(ccount, rcount);
    k_coarse<<<NPB, 256, 0, stream>>>(row, col, ccount, rcount);
    k_cscan<<<1, 512, 0, stream>>>(ccount, rcount, coff, roff, cpos, rpos, sums, off);
    k_part<<<NPB, 256, 0, stream>>>(row, col, cpos, rpos, partc, partr);
    k_bucket_col<<<NBUCK, 256, 0, stream>>>(partc, coff, off, srcw);
    k_bucket_row<<<NBUCK, 256, 0, stream>>>(partr, roff, dis);

    // ---- layer 1 ----
    k_lin1<<<(N_NODES + 7) / 8, 256, 0, stream>>>(x, W1, b1, dis, hs1b);
    k_gather1<<<(N_NODES + 3) / 4, 256, 0, stream>>>(srcw, off, dis, hs1b, hs2b);

    // ---- layer 2 (aggregate in 32-dim, lin2 fused into pool) ----
    k_gather2<<<(N_NODES + 3) / 4, 256, 0, stream>>>(srcw, off, dis, hs2b, G, Sd);

    // ---- pooling + head ----
    k_counts_bs<<<1, 64, 0, stream>>>(batch, cnts);
    k_lin2pool<<<(N_NODES + 255) / 256, 256, 0, stream>>>(G, Sd, W2, b2, batch, sums);
    k_final<<<1, 640, 0, stream>>>(sums, cnts, Wf, bf, out);
}